// Round 7
// baseline (136.441 us; speedup 1.0000x reference)
//
#include <hip/hip_runtime.h>
#include <hip/hip_bf16.h>
#include <cstdint>
#include <cstddef>

// Problem dims (fixed): B=4, NI=NO=256, DIN=DQ=DH=DOUT=256.
// out[b,i,j,:] = gelu(u[b,i,:] + v[b,j,:]) @ W2 + b2
//   u = (x@W_pre + b_pre)@W1[:256] + b1   (b1 folded into u)
//   v = (query@W_emb + b_emb)@W1[256:]

typedef __bf16  bf16x8 __attribute__((ext_vector_type(8)));
typedef float   f32x16 __attribute__((ext_vector_type(16)));

// tanh-approx gelu with exp2 constant pre-folded:
// gelu(x) ~= x / (1 + exp2(x*(-2.3022072 - 0.1029433*x^2)))
__device__ __forceinline__ float fast_gelu(float x) {
    const float x2 = x * x;
    const float m  = __builtin_fmaf(x2, -0.1029433f, -2.3022072f);
    const float e  = __builtin_amdgcn_exp2f(x * m);
    return x * __builtin_amdgcn_rcpf(1.0f + e);
}

// ---------------------------------------------------------------------------
// Prep kernel (one launch):
//   blocks [0,256):   u rows — x path (4 rows/block)
//   blocks [256,512): v rows — query path
//   blocks [512,576): W2T[n][k] = bf16(W2[k][n])  (4 n-cols/block)
// ---------------------------------------------------------------------------
__global__ __launch_bounds__(256) void prep_kernel(
    const float* __restrict__ x, const float* __restrict__ query,
    const float* __restrict__ W_pre, const float* __restrict__ b_pre,
    const float* __restrict__ W_emb, const float* __restrict__ b_emb,
    const float* __restrict__ W1, const float* __restrict__ b1,
    const float* __restrict__ W2,
    float* __restrict__ u, float* __restrict__ v,
    unsigned short* __restrict__ w2t)
{
    const int b = blockIdx.x;
    const int t = threadIdx.x;

    if (b >= 512) {                       // W2 transpose + bf16 convert
        const int n0 = (b - 512) * 4;
        const float4 wv = *reinterpret_cast<const float4*>(W2 + (size_t)t * 256 + n0);
        const float vals[4] = {wv.x, wv.y, wv.z, wv.w};
#pragma unroll
        for (int j = 0; j < 4; ++j) {
            const __bf16 bv = (__bf16)vals[j];
            w2t[(size_t)(n0 + j) * 256 + t] = __builtin_bit_cast(unsigned short, bv);
        }
        return;
    }

    const bool isq = (b >= 256);
    const float* __restrict__ A   = isq ? query : x;
    const float* __restrict__ Wa  = isq ? W_emb : W_pre;
    const float* __restrict__ ba  = isq ? b_emb : b_pre;
    const float* __restrict__ W1p = isq ? (W1 + 256 * 256) : W1;
    float* __restrict__ outp      = isq ? v : u;
    const int r0 = (isq ? (b - 256) : b) * 4;

    __shared__ float as[4][256];
    __shared__ float xs[4][256];

#pragma unroll
    for (int r = 0; r < 4; ++r)
        as[r][t] = A[(size_t)(r0 + r) * 256 + t];
    __syncthreads();

    float acc[4] = {0.f, 0.f, 0.f, 0.f};
    for (int k = 0; k < 256; ++k) {
        const float wv = Wa[(size_t)k * 256 + t];
#pragma unroll
        for (int r = 0; r < 4; ++r) acc[r] += as[r][k] * wv;
    }
    const float bav = ba[t];
#pragma unroll
    for (int r = 0; r < 4; ++r) xs[r][t] = acc[r] + bav;
    __syncthreads();

    float acc2[4] = {0.f, 0.f, 0.f, 0.f};
    for (int k = 0; k < 256; ++k) {
        const float wv = W1p[(size_t)k * 256 + t];
#pragma unroll
        for (int r = 0; r < 4; ++r) acc2[r] += xs[r][k] * wv;
    }
    const float b1v = isq ? 0.f : b1[t];
#pragma unroll
    for (int r = 0; r < 4; ++r)
        outp[(size_t)(r0 + r) * 256 + t] = acc2[r] + b1v;
}

// ---------------------------------------------------------------------------
// Fused main kernel — small tiles for occupancy (the TLP lever).
// Block = 256 threads = 4 waves; block tile = 128 j-rows x 128 cols.
// Grid = 1024 (b,i)-tiles x {row-half jh, col-half ch} = 4096 blocks,
// XCD-bijective swizzle so a tile's 4 quadrants share one XCD's L2.
// Wave w owns rows [w*32, +32) x all 128 block-cols: acc = 4 x f32x16 =
// 64 VGPR. LDS = W2T chunk [128 n][64 k] (16 KB) + H [128 r][64 k] (16 KB)
// = 32 KB -> with __launch_bounds__(256,4): ~4 blocks/CU = 16 waves/CU,
// 2x the TLP of rounds 4/5 (the structures stuck at ~90 us fused).
//
// Per 64-k chunk (single-buffered, 2 barriers):
//   stage W2T chunk via global_load_lds w16 (linear dest, inverse-swizzled
//   source granule); compute H = gelu(u+v) coalesced (lane -> k-pair,
//   2 whole rows per wave-instr), packed bf16x2 ds_write, XOR-swizzled;
//   barrier; 4 k-steps x (1 A-frag + 4 B-frag ds_read_b128 + 4 MFMA);
//   barrier. gelu computed once per H element per block (x2 globally
//   across col-halves — cheap VALU, hidden by TLP).
//
// mfma_f32_32x32x16_bf16 layouts (gfx950):
//   A: lane l holds A[l&31][(l>>5)*8 + e]
//   B: lane l holds B[(l>>5)*8 + e][l&31]
//   D: lane l reg r holds D[(r&3) + 8*(r>>2) + 4*(l>>5)][l&31]
// Stores: normal (L2 write-back) scalar dword, lane-consecutive cols.
// ---------------------------------------------------------------------------
__global__ __launch_bounds__(256, 4) void fused_kernel(
    const float* __restrict__ U, const float* __restrict__ V,
    const unsigned short* __restrict__ W2T, const float* __restrict__ b2,
    float* __restrict__ out)
{
    __shared__ uint4 wlds[1024];   // 16 KB: W2T chunk [128 n][8 granules]
    __shared__ uint4 hlds[1024];   // 16 KB: H tile    [128 r][8 granules]
    unsigned int* const h32 = reinterpret_cast<unsigned int*>(hlds);

    const int t    = threadIdx.x;
    const int lane = t & 63;
    const int w    = t >> 6;       // 0..3
    const int l31  = lane & 31;
    const int hi   = lane >> 5;    // 0..1

    // XCD-bijective swizzle: 4096 = 8 * 512; consecutive logical ids (the
    // 4 quadrants of a tile) land on the same XCD.
    const int bid = blockIdx.x;
    const int L   = (bid & 7) * 512 + (bid >> 3);
    const int tile = L >> 2;       // 0..1023 = (bb, ii)
    const int jh   = (L >> 1) & 1;
    const int ch   = L & 1;
    const int bb   = tile >> 8;
    const int n0   = ch * 128;     // global col base
    const int j0   = jh * 128;     // global row base

    const float* __restrict__ urow  = U + (size_t)tile * 256;
    const float* __restrict__ vbase = V + ((size_t)(bb * 256 + j0)) * 256;

    // H-compute mapping: d = k-pair index (k = kk+2d, 2d+1), rb = row base.
    const int d  = t & 31;
    const int rb = t >> 5;         // 0..7; rows rb + 8*p

    f32x16 acc[4];
#pragma unroll
    for (int i = 0; i < 4; ++i) acc[i] = (f32x16)0.f;

    for (int kk = 0; kk < 256; kk += 64) {
        // ---- stage W2T chunk (async, linear dest, pre-swizzled source) ----
#pragma unroll
        for (int it = 0; it < 4; ++it) {
            const int idx = it * 256 + t;    // linear LDS granule
            const int n   = idx >> 3;        // 0..127 local col
            const int gp  = idx & 7;         // LDS granule slot
            const int g   = gp ^ (n & 7);    // inverse-swizzled source granule
            __builtin_amdgcn_global_load_lds(
                (const __attribute__((address_space(1))) unsigned int*)
                    (W2T + (size_t)(n0 + n) * 256 + kk + g * 8),
                (__attribute__((address_space(3))) unsigned int*)(wlds + idx),
                16, 0, 0);
        }

        // ---- H tile: coalesced loads, gelu once, swizzled ds_write ----
        const float2 u2 = *reinterpret_cast<const float2*>(urow + kk + 2 * d);
#pragma unroll 1
        for (int pass = 0; pass < 2; ++pass) {   // 2 passes of 8 rows: VGPR cap
            float2 vv[8];
#pragma unroll
            for (int p = 0; p < 8; ++p) {
                const int row = rb + (pass * 8 + p) * 8;
                vv[p] = *reinterpret_cast<const float2*>(
                    vbase + (size_t)row * 256 + kk + 2 * d);
            }
#pragma unroll
            for (int p = 0; p < 8; ++p) {
                const int row = rb + (pass * 8 + p) * 8;
                union { unsigned int u32; __bf16 h[2]; } pk;
                pk.h[0] = (__bf16)fast_gelu(u2.x + vv[p].x);
                pk.h[1] = (__bf16)fast_gelu(u2.y + vv[p].y);
                h32[row * 32 + (((d >> 2) ^ (row & 7)) << 2) + (d & 3)] = pk.u32;
            }
        }
        __syncthreads();   // drains gll (vmcnt) + H writes

        // ---- MFMA: 4 k-steps ----
#pragma unroll
        for (int s = 0; s < 4; ++s) {
            const int gk = 2 * s + hi;       // k-granule within chunk
            const int arow = w * 32 + l31;
            const bf16x8 afrag = __builtin_bit_cast(
                bf16x8, hlds[arow * 8 + (gk ^ (arow & 7))]);
#pragma unroll
            for (int cg = 0; cg < 4; ++cg) {
                const int nloc = cg * 32 + l31;
                const bf16x8 bfrag = __builtin_bit_cast(
                    bf16x8, wlds[nloc * 8 + (gk ^ (nloc & 7))]);
                acc[cg] = __builtin_amdgcn_mfma_f32_32x32x16_bf16(
                    afrag, bfrag, acc[cg], 0, 0, 0);
            }
        }
        __syncthreads();
    }

    // ---- epilogue: out[row][col] = acc + b2[col] (normal stores, L2) ----
    const size_t obase = (size_t)tile << 16;
#pragma unroll
    for (int cg = 0; cg < 4; ++cg) {
        const int col = n0 + cg * 32 + l31;
        const float bv = b2[col];
#pragma unroll
        for (int rr = 0; rr < 16; ++rr) {
            const int row = j0 + w * 32 + 4 * hi + (rr & 3) + 8 * (rr >> 2);
            out[obase + (size_t)row * 256 + col] = acc[cg][rr] + bv;
        }
    }
}

// ---------------------------------------------------------------------------
extern "C" void kernel_launch(void* const* d_in, const int* in_sizes, int n_in,
                              void* d_out, int out_size, void* d_ws, size_t ws_size,
                              hipStream_t stream)
{
    const float* x     = (const float*)d_in[0];
    const float* query = (const float*)d_in[1];
    const float* W_pre = (const float*)d_in[2];
    const float* b_pre = (const float*)d_in[3];
    const float* W_emb = (const float*)d_in[4];
    const float* b_emb = (const float*)d_in[5];
    const float* W1    = (const float*)d_in[6];
    const float* b1    = (const float*)d_in[7];
    const float* W2    = (const float*)d_in[8];
    const float* b2    = (const float*)d_in[9];
    float* out = (float*)d_out;

    char* ws = (char*)d_ws;
    float* u            = (float*)(ws);                          // 1 MB
    float* v            = (float*)(ws + (1 << 20));              // 1 MB
    unsigned short* w2t = (unsigned short*)(ws + 2 * (1 << 20)); // 128 KB

    prep_kernel<<<576, 256, 0, stream>>>(x, query, W_pre, b_pre, W_emb, b_emb,
                                         W1, b1, W2, u, v, w2t);
    fused_kernel<<<4096, 256, 0, stream>>>(u, v, w2t, b2, out);
}

// Round 8
// 105.053 us; speedup vs baseline: 1.2988x; 1.2988x over previous
//
#include <hip/hip_runtime.h>
#include <hip/hip_bf16.h>
#include <cstdint>
#include <cstddef>

// Problem dims (fixed): B=4, NI=NO=256, DIN=DQ=DH=DOUT=256.
// out[b,i,j,:] = gelu(u[b,i,:] + v[b,j,:]) @ W2 + b2
//   u = (x@W_pre + b_pre)@W1[:256] + b1   (b1 folded into u)
//   v = (query@W_emb + b_emb)@W1[256:]

typedef __bf16  bf16x8 __attribute__((ext_vector_type(8)));
typedef float   f32x16 __attribute__((ext_vector_type(16)));

// tanh-approx gelu with exp2 constant pre-folded:
// gelu(x) ~= x / (1 + exp2(x*(-2.3022072 - 0.1029433*x^2)))
__device__ __forceinline__ float fast_gelu(float x) {
    const float x2 = x * x;
    const float m  = __builtin_fmaf(x2, -0.1029433f, -2.3022072f);
    const float e  = __builtin_amdgcn_exp2f(x * m);
    return x * __builtin_amdgcn_rcpf(1.0f + e);
}

// ---------------------------------------------------------------------------
// Prep kernel (one launch):
//   blocks [0,256):   u rows — x path (4 rows/block)
//   blocks [256,512): v rows — query path
//   blocks [512,576): W2T[n][k] = bf16(W2[k][n])  (4 n-cols/block)
// R1 measured the old serial-load version at ~42 us total: the k-loops
// exposed ~200cy L2 latency per iteration. This version double-buffers
// 8 weight rows in registers (prefetch k+8 while FMAing k) -> latency
// overlapped, prep ~6-10 us.
// ---------------------------------------------------------------------------
__global__ __launch_bounds__(256) void prep_kernel(
    const float* __restrict__ x, const float* __restrict__ query,
    const float* __restrict__ W_pre, const float* __restrict__ b_pre,
    const float* __restrict__ W_emb, const float* __restrict__ b_emb,
    const float* __restrict__ W1, const float* __restrict__ b1,
    const float* __restrict__ W2,
    float* __restrict__ u, float* __restrict__ v,
    unsigned short* __restrict__ w2t)
{
    const int b = blockIdx.x;
    const int t = threadIdx.x;

    if (b >= 512) {                       // W2 transpose + bf16 convert
        const int n0 = (b - 512) * 4;
        const float4 wv = *reinterpret_cast<const float4*>(W2 + (size_t)t * 256 + n0);
        const float vals[4] = {wv.x, wv.y, wv.z, wv.w};
#pragma unroll
        for (int j = 0; j < 4; ++j) {
            const __bf16 bv = (__bf16)vals[j];
            w2t[(size_t)(n0 + j) * 256 + t] = __builtin_bit_cast(unsigned short, bv);
        }
        return;
    }

    const bool isq = (b >= 256);
    const float* __restrict__ A   = isq ? query : x;
    const float* __restrict__ Wa  = isq ? W_emb : W_pre;
    const float* __restrict__ ba  = isq ? b_emb : b_pre;
    const float* __restrict__ W1p = isq ? (W1 + 256 * 256) : W1;
    float* __restrict__ outp      = isq ? v : u;
    const int r0 = (isq ? (b - 256) : b) * 4;

    __shared__ float as[4][256];
    __shared__ float xs[4][256];

#pragma unroll
    for (int r = 0; r < 4; ++r)
        as[r][t] = A[(size_t)(r0 + r) * 256 + t];
    __syncthreads();

    // ---- GEMM 1: acc[r] = as[r,:] @ Wa[:,t]  (8-deep reg prefetch) ----
    float acc[4] = {0.f, 0.f, 0.f, 0.f};
    {
        float wcur[8];
#pragma unroll
        for (int q = 0; q < 8; ++q) wcur[q] = Wa[(size_t)q * 256 + t];
        for (int k0 = 0; k0 < 248; k0 += 8) {
            float wnxt[8];
#pragma unroll
            for (int q = 0; q < 8; ++q)
                wnxt[q] = Wa[(size_t)(k0 + 8 + q) * 256 + t];
#pragma unroll
            for (int q = 0; q < 8; ++q)
#pragma unroll
                for (int r = 0; r < 4; ++r)
                    acc[r] = __builtin_fmaf(as[r][k0 + q], wcur[q], acc[r]);
#pragma unroll
            for (int q = 0; q < 8; ++q) wcur[q] = wnxt[q];
        }
#pragma unroll
        for (int q = 0; q < 8; ++q)
#pragma unroll
            for (int r = 0; r < 4; ++r)
                acc[r] = __builtin_fmaf(as[r][248 + q], wcur[q], acc[r]);
    }
    const float bav = ba[t];
#pragma unroll
    for (int r = 0; r < 4; ++r) xs[r][t] = acc[r] + bav;
    __syncthreads();

    // ---- GEMM 2: acc2[r] = xs[r,:] @ W1p[:,t]  (8-deep reg prefetch) ----
    float acc2[4] = {0.f, 0.f, 0.f, 0.f};
    {
        float wcur[8];
#pragma unroll
        for (int q = 0; q < 8; ++q) wcur[q] = W1p[(size_t)q * 256 + t];
        for (int k0 = 0; k0 < 248; k0 += 8) {
            float wnxt[8];
#pragma unroll
            for (int q = 0; q < 8; ++q)
                wnxt[q] = W1p[(size_t)(k0 + 8 + q) * 256 + t];
#pragma unroll
            for (int q = 0; q < 8; ++q)
#pragma unroll
                for (int r = 0; r < 4; ++r)
                    acc2[r] = __builtin_fmaf(xs[r][k0 + q], wcur[q], acc2[r]);
#pragma unroll
            for (int q = 0; q < 8; ++q) wcur[q] = wnxt[q];
        }
#pragma unroll
        for (int q = 0; q < 8; ++q)
#pragma unroll
            for (int r = 0; r < 4; ++r)
                acc2[r] = __builtin_fmaf(xs[r][248 + q], wcur[q], acc2[r]);
    }
    const float b1v = isq ? 0.f : b1[t];
#pragma unroll
    for (int r = 0; r < 4; ++r)
        outp[(size_t)(r0 + r) * 256 + t] = acc2[r] + b1v;
}

// ---------------------------------------------------------------------------
// Fused main kernel — IDENTICAL to round 4 (best measured: ~68 us).
// Block = 256 threads = 4 waves; computes 128 output rows (fixed b,i; 128 j)
// x 256 cols. Wave w owns rows [w*32, w*32+32) x all 256 cols.
// acc = 8 x f32x16 = 128 VGPR.
//
// Per 64-k chunk:
//  phase 1:
//   (a) W2T chunk [256n][64k] -> LDS via global_load_lds width-16 (async,
//       linear LDS dest; XOR swizzle applied by INVERSE-permuting the global
//       source granule, G21 both-sides rule).
//   (b) H tile [128r][64k] = gelu(u+v), coalesced: lane -> k-pair
//       (float2), iteration -> row; each dwordx2 load covers 2 whole rows
//       (2 x 256B). Lane packs 2 bf16 -> ds_write_b32, XOR-swizzled.
//       Overlaps with (a)'s in-flight DMA. gelu once per element.
//  phase 2: waves read A-frags (H) / B-frags (W2T) from swizzled LDS
//   (measured 0 bank conflicts) -> 8 mfma_32x32x16 per k-step x 4.
// mfma_f32_32x32x16_bf16 layouts (gfx950):
//   A: lane l holds A[l&31][(l>>5)*8 + e]
//   B: lane l holds B[(l>>5)*8 + e][l&31]
//   D: lane l reg r holds D[(r&3) + 8*(r>>2) + 4*(l>>5)][l&31]
// LDS 48 KB. launch_bounds(256,2).
// ---------------------------------------------------------------------------
__global__ __launch_bounds__(256, 2) void fused_kernel(
    const float* __restrict__ U, const float* __restrict__ V,
    const unsigned short* __restrict__ W2T, const float* __restrict__ b2,
    float* __restrict__ out)
{
    __shared__ uint4 wlds[2048];   // 32 KB: W2T chunk [256 n][64 k] bf16, swizzled
    __shared__ uint4 hlds[1024];   // 16 KB: H tile    [128 r][64 k] bf16, swizzled
    unsigned int* const hlds32 = reinterpret_cast<unsigned int*>(hlds);

    const int t    = threadIdx.x;
    const int lane = t & 63;
    const int w    = t >> 6;
    const int l31  = lane & 31;
    const int hi   = lane >> 5;    // 0..1

    const size_t r0 = (size_t)blockIdx.x * 128;
    const int bb = (int)(r0 >> 16);
    const int ii = (int)((r0 >> 8) & 255);
    const int j0 = (int)(r0 & 255);          // 0 or 128

    const float* __restrict__ urow  = U + ((size_t)(bb * 256 + ii)) * 256;
    const float* __restrict__ vbase = V + ((size_t)(bb * 256 + j0)) * 256;

    f32x16 acc[8];
#pragma unroll
    for (int i = 0; i < 8; ++i) acc[i] = (f32x16)0.f;

    for (int kk = 0; kk < 256; kk += 64) {
        // ---- phase 1a: async W2T chunk -> LDS (linear dest, pre-swizzled src)
#pragma unroll
        for (int it = 0; it < 8; ++it) {
            const int idx = it * 256 + t;     // granule index, wave-contiguous
            const int n   = idx >> 3;         // 0..255
            const int gp  = idx & 7;          // LDS granule slot (linear)
            const int g   = gp ^ (n & 7);     // source granule (inverse swizzle)
            __builtin_amdgcn_global_load_lds(
                (const __attribute__((address_space(1))) unsigned int*)
                    (W2T + (size_t)n * 256 + kk + g * 8),
                (__attribute__((address_space(3))) unsigned int*)
                    (wlds + idx),
                16, 0, 0);
        }

        // ---- phase 1b: H tile, coalesced (lane -> k-pair, iter -> row) ----
        const float2 uv2 = *reinterpret_cast<const float2*>(urow + kk + 2 * l31);
        float2 vv[16];
#pragma unroll
        for (int p = 0; p < 16; ++p) {
            const int row = w * 32 + p * 2 + hi;          // 2 rows per instr
            vv[p] = *reinterpret_cast<const float2*>(vbase + (size_t)row * 256 + kk + 2 * l31);
        }
#pragma unroll
        for (int p = 0; p < 16; ++p) {
            const int row = w * 32 + p * 2 + hi;
            union { unsigned int u32; __bf16 h[2]; } pk;
            pk.h[0] = (__bf16)fast_gelu(uv2.x + vv[p].x);
            pk.h[1] = (__bf16)fast_gelu(uv2.y + vv[p].y);
            const int d = l31;
            hlds32[row * 32 + (((d >> 2) ^ (row & 7)) << 2) + (d & 3)] = pk.u32;
        }
        __syncthreads();   // drains global_load_lds (vmcnt) + LDS writes

        // ---- phase 2: MFMA ----
#pragma unroll
        for (int s = 0; s < 4; ++s) {
            const int gk = 2 * s + hi;        // k-granule within chunk
            const int arow = w * 32 + l31;
            const bf16x8 afrag = __builtin_bit_cast(
                bf16x8, hlds[arow * 8 + (gk ^ (arow & 7))]);
#pragma unroll
            for (int cg = 0; cg < 8; ++cg) {
                const int col = cg * 32 + l31;
                const bf16x8 bfrag = __builtin_bit_cast(
                    bf16x8, wlds[col * 8 + (gk ^ (col & 7))]);
                acc[cg] = __builtin_amdgcn_mfma_f32_32x32x16_bf16(
                    afrag, bfrag, acc[cg], 0, 0, 0);
            }
        }
        __syncthreads();
    }

    // ---- epilogue: out[row][col] = acc + b2[col], nontemporal ----
#pragma unroll
    for (int cg = 0; cg < 8; ++cg) {
        const int col = cg * 32 + l31;
        const float bv = b2[col];
#pragma unroll
        for (int rr = 0; rr < 16; ++rr) {
            const int row = w * 32 + 4 * hi + (rr & 3) + 8 * (rr >> 2);
            __builtin_nontemporal_store(acc[cg][rr] + bv,
                                        out + (r0 + row) * 256 + col);
        }
    }
}

// ---------------------------------------------------------------------------
extern "C" void kernel_launch(void* const* d_in, const int* in_sizes, int n_in,
                              void* d_out, int out_size, void* d_ws, size_t ws_size,
                              hipStream_t stream)
{
    const float* x     = (const float*)d_in[0];
    const float* query = (const float*)d_in[1];
    const float* W_pre = (const float*)d_in[2];
    const float* b_pre = (const float*)d_in[3];
    const float* W_emb = (const float*)d_in[4];
    const float* b_emb = (const float*)d_in[5];
    const float* W1    = (const float*)d_in[6];
    const float* b1    = (const float*)d_in[7];
    const float* W2    = (const float*)d_in[8];
    const float* b2    = (const float*)d_in[9];
    float* out = (float*)d_out;

    char* ws = (char*)d_ws;
    float* u            = (float*)(ws);                          // 1 MB
    float* v            = (float*)(ws + (1 << 20));              // 1 MB
    unsigned short* w2t = (unsigned short*)(ws + 2 * (1 << 20)); // 128 KB

    prep_kernel<<<576, 256, 0, stream>>>(x, query, W_pre, b_pre, W_emb, b_emb,
                                         W1, b1, W2, u, v, w2t);
    fused_kernel<<<2048, 256, 0, stream>>>(u, v, w2t, b2, out);
}